// Round 3
// baseline (275.626 us; speedup 1.0000x reference)
//
#include <hip/hip_runtime.h>
#include <hip/hip_bf16.h>
#include <stdint.h>

// ---------------------------------------------------------------------------
// CrossAttention B=4 N=512 M=2048 C=1024 H=16 D=64, bf16 MFMA fp32 accum.
// R3: GEMM epilogue staged through LDS (coalesced u16x8 stores); V^T written
// directly by the V-GEMM (transpose kernel deleted); attention q-tile 32 for
// 4 blocks/CU + double-buffered P LDS.
// ---------------------------------------------------------------------------

typedef __attribute__((ext_vector_type(4))) float f32x4;
typedef __attribute__((ext_vector_type(8))) __bf16 bf16x8;
typedef __attribute__((ext_vector_type(8))) unsigned short u16x8;

#define DEVI __device__ __forceinline__

// SCALE * log2(e): folded into Wq cast so QK^T scores land in log2 units.
#define QSC (0.125f * 1.44269504088896f)

DEVI f32x4 mfma16(u16x8 a, u16x8 b, f32x4 c) {
  return __builtin_amdgcn_mfma_f32_16x16x32_bf16(
      __builtin_bit_cast(bf16x8, a), __builtin_bit_cast(bf16x8, b), c, 0, 0, 0);
}

// round-to-nearest-even fp32 -> bf16
DEVI unsigned short f2bf(float f) {
  union { float f; unsigned int u; } x; x.f = f;
  unsigned int u = x.u;
  return (unsigned short)((u + 0x7fffu + ((u >> 16) & 1u)) >> 16);
}

DEVI float exp2_fast(float x) {
#if __has_builtin(__builtin_amdgcn_exp2f)
  return __builtin_amdgcn_exp2f(x);
#else
  return exp2f(x);
#endif
}

// async global->LDS, 16 bytes per lane (global_load_lds_dwordx4)
DEVI void llds16(const void* g, void* l) {
  __builtin_amdgcn_global_load_lds(
      (const __attribute__((address_space(1))) void*)g,
      (__attribute__((address_space(3))) void*)l, 16, 0, 0);
}

// ---------------------------------------------------------------------------
// One kernel casts all six fp32 inputs to bf16. Wq gets QSC folded in.
__global__ __launch_bounds__(256)
void cast_fused(const float* __restrict__ x, const float* __restrict__ ctx,
                const float* __restrict__ wq, const float* __restrict__ wk,
                const float* __restrict__ wv, const float* __restrict__ wo,
                unsigned short* __restrict__ xb, unsigned short* __restrict__ cb,
                unsigned short* __restrict__ wqb, unsigned short* __restrict__ wkb,
                unsigned short* __restrict__ wvb, unsigned short* __restrict__ wob) {
  int bid = blockIdx.x;
  const float* src; unsigned short* dst; float scale = 1.f;
  if (bid < 2048)        { src = x;   dst = xb; }
  else if (bid < 10240)  { src = ctx; dst = cb;  bid -= 2048; }
  else if (bid < 11264)  { src = wq;  dst = wqb; bid -= 10240; scale = QSC; }
  else if (bid < 12288)  { src = wk;  dst = wkb; bid -= 11264; }
  else if (bid < 13312)  { src = wv;  dst = wvb; bid -= 12288; }
  else                   { src = wo;  dst = wob; bid -= 13312; }
  int idx = (bid * 256 + threadIdx.x) * 4;
  const float4 v = *(const float4*)(src + idx);
  ushort4 o;
  o.x = f2bf(v.x * scale); o.y = f2bf(v.y * scale);
  o.z = f2bf(v.z * scale); o.w = f2bf(v.w * scale);
  *(ushort4*)(dst + idx) = o;
}

// ---------------------------------------------------------------------------
// GEMM body: C = A[.,1024] @ W[1024,1024]^T + bias*bscale. 128x128 tile, BK=64.
// mode 0: bf16 out permuted to [B,H,S,64] (S = 1<<logS), LDS-staged epilogue.
// mode 1: fp32 out row-major [.,1024], direct stores.
// mode 2: bf16 out transposed to [B*16+h][d][m] (V^T), LDS-staged epilogue.
DEVI void gemm_body(const unsigned short* __restrict__ A,
                    const unsigned short* __restrict__ W,
                    const float* __restrict__ bias,
                    void* __restrict__ Cout,
                    int bm, int bn, int logS, float bscale, int mode) {
  constexpr int K = 1024;
  __shared__ __align__(16) unsigned short sh[128 * 64 * 2];  // As | Bs, then C-stage
  unsigned short* As = sh;
  unsigned short* Bs = sh + 128 * 64;

  const int tid = threadIdx.x;
  const int wave = tid >> 6, lane = tid & 63;
  const int l15 = lane & 15, quad = lane >> 4;
  const int wm = wave & 1, wn = wave >> 1;

  f32x4 acc[4][4] = {};

  for (int k0 = 0; k0 < K; k0 += 64) {
    __syncthreads();
#pragma unroll
    for (int c = 0; c < 4; ++c) {
      int s = c * 256 + tid;
      int m = s >> 3;
      int k8 = (s & 7) ^ (m & 7);
      llds16(A + (size_t)(bm + m) * K + k0 + k8 * 8, &As[s * 8]);
      llds16(W + (size_t)(bn + m) * K + k0 + k8 * 8, &Bs[s * 8]);
    }
    __syncthreads();
#pragma unroll
    for (int ks = 0; ks < 2; ++ks) {
      u16x8 af[4], bf[4];
      const int k8 = ks * 4 + quad;
#pragma unroll
      for (int i = 0; i < 4; ++i) {
        int m = wm * 64 + i * 16 + l15;
        af[i] = *(const u16x8*)(&As[(m * 8 + (k8 ^ (m & 7))) * 8]);
        int n = wn * 64 + i * 16 + l15;
        bf[i] = *(const u16x8*)(&Bs[(n * 8 + (k8 ^ (n & 7))) * 8]);
      }
#pragma unroll
      for (int mi = 0; mi < 4; ++mi)
#pragma unroll
        for (int ni = 0; ni < 4; ++ni)
          acc[mi][ni] = mfma16(af[mi], bf[ni], acc[mi][ni]);
    }
  }

  if (mode == 1) {  // fp32 row-major direct
#pragma unroll
    for (int mi = 0; mi < 4; ++mi)
#pragma unroll
      for (int ni = 0; ni < 4; ++ni)
#pragma unroll
        for (int r = 0; r < 4; ++r) {
          int row = bm + wm * 64 + mi * 16 + quad * 4 + r;
          int col = bn + wn * 64 + ni * 16 + l15;
          ((float*)Cout)[(size_t)row * 1024 + col] = acc[mi][ni][r] + bias[col] * bscale;
        }
    return;
  }

  // bf16 epilogues via LDS, two 64-row phases (reuse sh as C-stage)
  unsigned short* cst = sh;
  __syncthreads();
  for (int half = 0; half < 2; ++half) {
    if (wm == half) {
#pragma unroll
      for (int mi = 0; mi < 4; ++mi)
#pragma unroll
        for (int ni = 0; ni < 4; ++ni)
#pragma unroll
          for (int r = 0; r < 4; ++r) {
            int lrow = mi * 16 + quad * 4 + r;          // 0..63
            int lcol = wn * 64 + ni * 16 + l15;         // 0..127
            int col = bn + lcol;
            unsigned short bv = f2bf(acc[mi][ni][r] + bias[col] * bscale);
            if (mode == 0) cst[lrow * 136 + lcol] = bv;
            else           cst[lcol * 72 + lrow] = bv;  // transposed
          }
    }
    __syncthreads();
    if (mode == 0) {
      // [B,H,S,64]: coalesced u16x8 along d
      int lrow = tid >> 2, cc = (tid & 3) * 32;
      int row = bm + half * 64 + lrow;
      int b = row >> logS, sl = row & ((1 << logS) - 1);
#pragma unroll
      for (int j = 0; j < 4; ++j) {
        int col = bn + cc + j * 8;
        int h = col >> 6, d = col & 63;
        *(u16x8*)&((unsigned short*)Cout)[(((size_t)(b * 16 + h) << logS) + sl) * 64 + d] =
            *(const u16x8*)&cst[lrow * 136 + cc + j * 8];
      }
    } else {
      // V^T [bh][d][2048]: coalesced u16x8 along m
      int c = tid >> 1, rc = (tid & 1) * 32;
      int gc = bn + c, h = gc >> 6, d = gc & 63;
      int b = bm >> 11;
      size_t base = ((size_t)(b * 16 + h) * 64 + d) * 2048 + (bm & 2047) + half * 64 + rc;
#pragma unroll
      for (int j = 0; j < 4; ++j)
        *(u16x8*)&((unsigned short*)Cout)[base + j * 8] =
            *(const u16x8*)&cst[c * 72 + rc + j * 8];
    }
    __syncthreads();
  }
}

// Fused Q/K/V projection. Grid (64, 18).
// y in [0,8): K tiles (mode 0); y in [8,16): V^T tiles (mode 2); y 16,17: Q.
__global__ __launch_bounds__(256)
void gemm_qkv(const unsigned short* __restrict__ xb,
              const unsigned short* __restrict__ cb,
              const unsigned short* __restrict__ wq,
              const unsigned short* __restrict__ wk,
              const unsigned short* __restrict__ wv,
              const float* __restrict__ bq, const float* __restrict__ bk,
              const float* __restrict__ bv,
              unsigned short* __restrict__ qh, unsigned short* __restrict__ kh,
              unsigned short* __restrict__ vt) {
  const int x = blockIdx.x, y = blockIdx.y;
  if (y < 8)
    gemm_body(cb, wk, bk, kh, x * 128, y * 128, 11, 1.f, 0);
  else if (y < 16)
    gemm_body(cb, wv, bv, vt, x * 128, (y - 8) * 128, 11, 1.f, 2);
  else
    gemm_body(xb, wq, bq, qh, (x & 15) * 128, (y - 16) * 512 + (x >> 4) * 128,
              9, QSC, 0);
}

// Output projection: fp32 out. Grid (16, 8).
__global__ __launch_bounds__(256)
void gemm_o(const unsigned short* __restrict__ ah,
            const unsigned short* __restrict__ wo,
            const float* __restrict__ bo, float* __restrict__ out) {
  gemm_body(ah, wo, bo, out, blockIdx.x * 128, blockIdx.y * 128, 0, 1.f, 1);
}

// ---------------------------------------------------------------------------
// Split-K flash attention. Grid (64 bh, 16 qblk) = 1024 blocks (4/CU).
// Block = 4 waves; wave w covers keys {w*64 + 256t}; all waves share the 32
// q rows. No barriers in the main loop; combine at end via LDS.
// Scores arrive in log2 units (Wq pre-scaled by QSC).
__global__ __launch_bounds__(256, 4)
void attn_kernel(const unsigned short* __restrict__ Q,   // [64][512][64]
                 const unsigned short* __restrict__ K,   // [64][2048][64]
                 const unsigned short* __restrict__ Vt,  // [64][64][2048]
                 const int* __restrict__ mask,           // [4][2048]
                 unsigned short* __restrict__ O) {       // [4][512][1024]
  __shared__ float bias_lds[2048];
  __shared__ __align__(16) unsigned short p_lds[4][2][16 * 72];  // dbuf by qg
  __shared__ float ml_lds[2][4][32];
  __shared__ __align__(16) float o_comb[32][68];

  const int tid = threadIdx.x;
  const int wave = tid >> 6, lane = tid & 63;
  const int l15 = lane & 15, quad = lane >> 4;
  const int bh = blockIdx.x, b = bh >> 4, h = bh & 15;
  const int q0 = blockIdx.y * 32;

  {  // mask -> additive bias
    const int* mb = mask + b * 2048;
    for (int i = tid; i < 2048; i += 256)
      bias_lds[i] = mb[i] ? 0.f : -1e30f;
  }
  __syncthreads();

  const unsigned short* Qb = Q + ((size_t)bh * 512 + q0) * 64;
  const unsigned short* Kb = K + (size_t)bh * (2048 * 64);
  const unsigned short* Vb = Vt + (size_t)bh * (64 * 2048);

  u16x8 aq[2][2];
#pragma unroll
  for (int qg = 0; qg < 2; ++qg)
#pragma unroll
    for (int ks = 0; ks < 2; ++ks)
      aq[qg][ks] = *(const u16x8*)(Qb + (qg * 16 + l15) * 64 + ks * 32 + quad * 8);

  f32x4 o_acc[2][4] = {};
  float m_s[2], l_s[2];
#pragma unroll
  for (int qg = 0; qg < 2; ++qg) { m_s[qg] = -3e30f; l_s[qg] = 0.f; }

#pragma unroll 1
  for (int t = 0; t < 8; ++t) {
    const int kb = wave * 64 + t * 256;

    u16x8 kf[2][4], vf[2][4];
#pragma unroll
    for (int ns = 0; ns < 4; ++ns)
#pragma unroll
      for (int ks = 0; ks < 2; ++ks)
        kf[ks][ns] = *(const u16x8*)(Kb + (size_t)(kb + ns * 16 + l15) * 64 + ks * 32 + quad * 8);
#pragma unroll
    for (int nd = 0; nd < 4; ++nd)
#pragma unroll
      for (int ks = 0; ks < 2; ++ks)
        vf[ks][nd] = *(const u16x8*)(Vb + (size_t)(nd * 16 + l15) * 2048 + kb + ks * 32 + quad * 8);
    f32x4 bfr[4];
#pragma unroll
    for (int ns = 0; ns < 4; ++ns)
      bfr[ns] = *(const f32x4*)&bias_lds[kb + ns * 16 + quad * 4];

#pragma unroll
    for (int qg = 0; qg < 2; ++qg) {
      // S^T tile: D[key = ns*16+quad*4+r][q = l15]
      f32x4 sfr[4];
#pragma unroll
      for (int ns = 0; ns < 4; ++ns) {
        f32x4 sa = {0.f, 0.f, 0.f, 0.f};
#pragma unroll
        for (int ks = 0; ks < 2; ++ks)
          sa = mfma16(kf[ks][ns], aq[qg][ks], sa);
        sfr[ns] = sa;
      }

      float s[4][4], tmax = -3e30f;
#pragma unroll
      for (int ns = 0; ns < 4; ++ns)
#pragma unroll
        for (int r = 0; r < 4; ++r) {
          s[ns][r] = sfr[ns][r] + bfr[ns][r];
          tmax = fmaxf(tmax, s[ns][r]);
        }
      tmax = fmaxf(tmax, __shfl_xor(tmax, 16, 64));
      tmax = fmaxf(tmax, __shfl_xor(tmax, 32, 64));

      const float mn = fmaxf(m_s[qg], tmax);
      const float alpha = exp2_fast(m_s[qg] - mn);
      m_s[qg] = mn;

      float rsum = 0.f;
#pragma unroll
      for (int ns = 0; ns < 4; ++ns) {
        unsigned int pr[4];
#pragma unroll
        for (int r = 0; r < 4; ++r) {
          float p = exp2_fast(s[ns][r] - mn);
          unsigned int u = __builtin_bit_cast(unsigned int, p) & 0xffff0000u;
          rsum += __builtin_bit_cast(float, u);  // sum TRUNCATED p: consistent with PV
          pr[r] = u;
        }
        uint2 pw;
        pw.x = __builtin_amdgcn_perm(pr[1], pr[0], 0x07060302u);
        pw.y = __builtin_amdgcn_perm(pr[3], pr[2], 0x07060302u);
        *(uint2*)&p_lds[wave][qg][l15 * 72 + ns * 16 + quad * 4] = pw;
      }
      rsum += __shfl_xor(rsum, 16, 64);
      rsum += __shfl_xor(rsum, 32, 64);
      l_s[qg] = l_s[qg] * alpha + rsum;

      float ar[4];
#pragma unroll
      for (int r = 0; r < 4; ++r) ar[r] = __shfl(alpha, quad * 4 + r, 64);
#pragma unroll
      for (int nd = 0; nd < 4; ++nd)
#pragma unroll
        for (int r = 0; r < 4; ++r) o_acc[qg][nd][r] *= ar[r];

#pragma unroll
      for (int ks = 0; ks < 2; ++ks) {
        u16x8 pf = *(const u16x8*)&p_lds[wave][qg][l15 * 72 + ks * 32 + quad * 8];
#pragma unroll
        for (int nd = 0; nd < 4; ++nd)
          o_acc[qg][nd] = mfma16(pf, vf[ks][nd], o_acc[qg][nd]);
      }
    }
  }

  // ---- combine the 4 waves' partial (m,l,o) ----
  if (quad == 0) {
#pragma unroll
    for (int qg = 0; qg < 2; ++qg) {
      ml_lds[0][wave][qg * 16 + l15] = m_s[qg];
      ml_lds[1][wave][qg * 16 + l15] = l_s[qg];
    }
  }
  __syncthreads();

  for (int w = 0; w < 4; ++w) {
    if (wave == w) {
#pragma unroll
      for (int qg = 0; qg < 2; ++qg) {
#pragma unroll
        for (int r = 0; r < 4; ++r) {
          const int q = qg * 16 + quad * 4 + r;
          float mstar = fmaxf(fmaxf(ml_lds[0][0][q], ml_lds[0][1][q]),
                              fmaxf(ml_lds[0][2][q], ml_lds[0][3][q]));
          float sc = exp2_fast(ml_lds[0][wave][q] - mstar);
#pragma unroll
          for (int nd = 0; nd < 4; ++nd) {
            const int d = nd * 16 + l15;
            float v = o_acc[qg][nd][r] * sc;
            if (w == 0) o_comb[q][d] = v;
            else        o_comb[q][d] += v;
          }
        }
      }
    }
    __syncthreads();
  }

  // ---- final normalize + store (one u16x8 per thread) ----
  {
    const int q = tid >> 3, dc = (tid & 7) * 8;
    float mstar = fmaxf(fmaxf(ml_lds[0][0][q], ml_lds[0][1][q]),
                        fmaxf(ml_lds[0][2][q], ml_lds[0][3][q]));
    float lstar = ml_lds[1][0][q] * exp2_fast(ml_lds[0][0][q] - mstar)
                + ml_lds[1][1][q] * exp2_fast(ml_lds[0][1][q] - mstar)
                + ml_lds[1][2][q] * exp2_fast(ml_lds[0][2][q] - mstar)
                + ml_lds[1][3][q] * exp2_fast(ml_lds[0][3][q] - mstar);
    const float inv = 1.f / lstar;
    u16x8 o1;
#pragma unroll
    for (int j = 0; j < 8; ++j) o1[j] = f2bf(o_comb[q][dc + j] * inv);
    *(u16x8*)(O + ((size_t)(b * 512 + q0 + q)) * 1024 + h * 64 + dc) = o1;
  }
}

// ---------------------------------------------------------------------------
extern "C" void kernel_launch(void* const* d_in, const int* in_sizes, int n_in,
                              void* d_out, int out_size, void* d_ws, size_t ws_size,
                              hipStream_t stream) {
  const float* x   = (const float*)d_in[0];
  const float* ctx = (const float*)d_in[1];
  const int* mask  = (const int*)d_in[2];
  const float* Wq  = (const float*)d_in[3];
  const float* bq  = (const float*)d_in[4];
  const float* Wk  = (const float*)d_in[5];
  const float* bk  = (const float*)d_in[6];
  const float* Wv  = (const float*)d_in[7];
  const float* bv  = (const float*)d_in[8];
  const float* Wo  = (const float*)d_in[9];
  const float* bo  = (const float*)d_in[10];

  char* ws = (char*)d_ws;
  // [MB] xb 0-4, cb 4-20, w 20-28, qh 28-32, kh 32-48, vt 48-64, ah 64-68.
  unsigned short* xb  = (unsigned short*)(ws + ((size_t)0  << 20));
  unsigned short* cb  = (unsigned short*)(ws + ((size_t)4  << 20));
  unsigned short* wqb = (unsigned short*)(ws + ((size_t)20 << 20));
  unsigned short* wkb = (unsigned short*)(ws + ((size_t)22 << 20));
  unsigned short* wvb = (unsigned short*)(ws + ((size_t)24 << 20));
  unsigned short* wob = (unsigned short*)(ws + ((size_t)26 << 20));
  unsigned short* qh  = (unsigned short*)(ws + ((size_t)28 << 20));
  unsigned short* kh  = (unsigned short*)(ws + ((size_t)32 << 20));
  unsigned short* vt  = (unsigned short*)(ws + ((size_t)48 << 20));
  unsigned short* ah  = (unsigned short*)(ws + ((size_t)64 << 20));

  cast_fused<<<14336, 256, 0, stream>>>(x, ctx, Wq, Wk, Wv, Wo,
                                        xb, cb, wqb, wkb, wvb, wob);
  gemm_qkv<<<dim3(64, 18), 256, 0, stream>>>(xb, cb, wqb, wkb, wvb,
                                             bq, bk, bv, qh, kh, vt);
  attn_kernel<<<dim3(64, 16), 256, 0, stream>>>(qh, kh, vt, mask, ah);
  gemm_o<<<dim3(16, 8), 256, 0, stream>>>(ah, wob, bo, (float*)d_out);
}

// Round 5
// 256.395 us; speedup vs baseline: 1.0750x; 1.0750x over previous
//
#include <hip/hip_runtime.h>
#include <hip/hip_bf16.h>
#include <stdint.h>

// ---------------------------------------------------------------------------
// CrossAttention B=4 N=512 M=2048 C=1024 H=16 D=64, bf16 MFMA fp32 accum.
// R5: R4 with p_lds stride reverted 74 -> 72. The stride MUST be a multiple
// of 8 u16 (16 B) so the u16x8 ds_read_b128 of P stays 16-byte aligned --
// PS=74 made odd q-rows 4-byte aligned => misaligned b128 => R4's absmax 1.6.
// Retained from R4: q-tile 64 (4 qg ILP chains), cross-iteration K register
// prefetch (no barriers in loop => loads stay in flight), fixed-max softmax
// (-8 shift folded into mask bias), bias via MFMA C-init.
// ---------------------------------------------------------------------------

typedef __attribute__((ext_vector_type(4))) float f32x4;
typedef __attribute__((ext_vector_type(8))) __bf16 bf16x8;
typedef __attribute__((ext_vector_type(8))) unsigned short u16x8;

#define DEVI __device__ __forceinline__

// SCALE * log2(e): folded into Wq cast so QK^T scores land in log2 units.
#define QSC (0.125f * 1.44269504088896f)

DEVI f32x4 mfma16(u16x8 a, u16x8 b, f32x4 c) {
  return __builtin_amdgcn_mfma_f32_16x16x32_bf16(
      __builtin_bit_cast(bf16x8, a), __builtin_bit_cast(bf16x8, b), c, 0, 0, 0);
}

// round-to-nearest-even fp32 -> bf16
DEVI unsigned short f2bf(float f) {
  union { float f; unsigned int u; } x; x.f = f;
  unsigned int u = x.u;
  return (unsigned short)((u + 0x7fffu + ((u >> 16) & 1u)) >> 16);
}

DEVI float exp2_fast(float x) {
#if __has_builtin(__builtin_amdgcn_exp2f)
  return __builtin_amdgcn_exp2f(x);
#else
  return exp2f(x);
#endif
}

// async global->LDS, 16 bytes per lane (global_load_lds_dwordx4)
DEVI void llds16(const void* g, void* l) {
  __builtin_amdgcn_global_load_lds(
      (const __attribute__((address_space(1))) void*)g,
      (__attribute__((address_space(3))) void*)l, 16, 0, 0);
}

// ---------------------------------------------------------------------------
// One kernel casts all six fp32 inputs to bf16. Wq gets QSC folded in.
__global__ __launch_bounds__(256)
void cast_fused(const float* __restrict__ x, const float* __restrict__ ctx,
                const float* __restrict__ wq, const float* __restrict__ wk,
                const float* __restrict__ wv, const float* __restrict__ wo,
                unsigned short* __restrict__ xb, unsigned short* __restrict__ cb,
                unsigned short* __restrict__ wqb, unsigned short* __restrict__ wkb,
                unsigned short* __restrict__ wvb, unsigned short* __restrict__ wob) {
  int bid = blockIdx.x;
  const float* src; unsigned short* dst; float scale = 1.f;
  if (bid < 2048)        { src = x;   dst = xb; }
  else if (bid < 10240)  { src = ctx; dst = cb;  bid -= 2048; }
  else if (bid < 11264)  { src = wq;  dst = wqb; bid -= 10240; scale = QSC; }
  else if (bid < 12288)  { src = wk;  dst = wkb; bid -= 11264; }
  else if (bid < 13312)  { src = wv;  dst = wvb; bid -= 12288; }
  else                   { src = wo;  dst = wob; bid -= 13312; }
  int idx = (bid * 256 + threadIdx.x) * 4;
  const float4 v = *(const float4*)(src + idx);
  ushort4 o;
  o.x = f2bf(v.x * scale); o.y = f2bf(v.y * scale);
  o.z = f2bf(v.z * scale); o.w = f2bf(v.w * scale);
  *(ushort4*)(dst + idx) = o;
}

// ---------------------------------------------------------------------------
// GEMM body: C = A[.,1024] @ W[1024,1024]^T + bias*bscale. 128x128 tile, BK=64.
// mode 0: bf16 out permuted to [B,H,S,64] (S = 1<<logS), LDS-staged epilogue.
// mode 1: fp32 out row-major [.,1024], direct stores.
// mode 2: bf16 out transposed to [B*16+h][d][m] (V^T), LDS-staged epilogue.
DEVI void gemm_body(const unsigned short* __restrict__ A,
                    const unsigned short* __restrict__ W,
                    const float* __restrict__ bias,
                    void* __restrict__ Cout,
                    int bm, int bn, int logS, float bscale, int mode) {
  constexpr int K = 1024;
  __shared__ __align__(16) unsigned short sh[128 * 64 * 2];  // As | Bs, then C-stage
  unsigned short* As = sh;
  unsigned short* Bs = sh + 128 * 64;

  const int tid = threadIdx.x;
  const int wave = tid >> 6, lane = tid & 63;
  const int l15 = lane & 15, quad = lane >> 4;
  const int wm = wave & 1, wn = wave >> 1;

  f32x4 acc[4][4] = {};

  for (int k0 = 0; k0 < K; k0 += 64) {
    __syncthreads();
#pragma unroll
    for (int c = 0; c < 4; ++c) {
      int s = c * 256 + tid;
      int m = s >> 3;
      int k8 = (s & 7) ^ (m & 7);
      llds16(A + (size_t)(bm + m) * K + k0 + k8 * 8, &As[s * 8]);
      llds16(W + (size_t)(bn + m) * K + k0 + k8 * 8, &Bs[s * 8]);
    }
    __syncthreads();
#pragma unroll
    for (int ks = 0; ks < 2; ++ks) {
      u16x8 af[4], bf[4];
      const int k8 = ks * 4 + quad;
#pragma unroll
      for (int i = 0; i < 4; ++i) {
        int m = wm * 64 + i * 16 + l15;
        af[i] = *(const u16x8*)(&As[(m * 8 + (k8 ^ (m & 7))) * 8]);
        int n = wn * 64 + i * 16 + l15;
        bf[i] = *(const u16x8*)(&Bs[(n * 8 + (k8 ^ (n & 7))) * 8]);
      }
#pragma unroll
      for (int mi = 0; mi < 4; ++mi)
#pragma unroll
        for (int ni = 0; ni < 4; ++ni)
          acc[mi][ni] = mfma16(af[mi], bf[ni], acc[mi][ni]);
    }
  }

  if (mode == 1) {  // fp32 row-major direct
#pragma unroll
    for (int mi = 0; mi < 4; ++mi)
#pragma unroll
      for (int ni = 0; ni < 4; ++ni)
#pragma unroll
        for (int r = 0; r < 4; ++r) {
          int row = bm + wm * 64 + mi * 16 + quad * 4 + r;
          int col = bn + wn * 64 + ni * 16 + l15;
          ((float*)Cout)[(size_t)row * 1024 + col] = acc[mi][ni][r] + bias[col] * bscale;
        }
    return;
  }

  // bf16 epilogues via LDS, two 64-row phases (reuse sh as C-stage)
  unsigned short* cst = sh;
  __syncthreads();
  for (int half = 0; half < 2; ++half) {
    if (wm == half) {
#pragma unroll
      for (int mi = 0; mi < 4; ++mi)
#pragma unroll
        for (int ni = 0; ni < 4; ++ni)
#pragma unroll
          for (int r = 0; r < 4; ++r) {
            int lrow = mi * 16 + quad * 4 + r;          // 0..63
            int lcol = wn * 64 + ni * 16 + l15;         // 0..127
            int col = bn + lcol;
            unsigned short bv = f2bf(acc[mi][ni][r] + bias[col] * bscale);
            if (mode == 0) cst[lrow * 136 + lcol] = bv;
            else           cst[lcol * 72 + lrow] = bv;  // transposed
          }
    }
    __syncthreads();
    if (mode == 0) {
      // [B,H,S,64]: coalesced u16x8 along d
      int lrow = tid >> 2, cc = (tid & 3) * 32;
      int row = bm + half * 64 + lrow;
      int b = row >> logS, sl = row & ((1 << logS) - 1);
#pragma unroll
      for (int j = 0; j < 4; ++j) {
        int col = bn + cc + j * 8;
        int h = col >> 6, d = col & 63;
        *(u16x8*)&((unsigned short*)Cout)[(((size_t)(b * 16 + h) << logS) + sl) * 64 + d] =
            *(const u16x8*)&cst[lrow * 136 + cc + j * 8];
      }
    } else {
      // V^T [bh][d][2048]: coalesced u16x8 along m
      int c = tid >> 1, rc = (tid & 1) * 32;
      int gc = bn + c, h = gc >> 6, d = gc & 63;
      int b = bm >> 11;
      size_t base = ((size_t)(b * 16 + h) * 64 + d) * 2048 + (bm & 2047) + half * 64 + rc;
#pragma unroll
      for (int j = 0; j < 4; ++j)
        *(u16x8*)&((unsigned short*)Cout)[base + j * 8] =
            *(const u16x8*)&cst[c * 72 + rc + j * 8];
    }
    __syncthreads();
  }
}

// Fused Q/K/V projection. Grid (64, 18).
__global__ __launch_bounds__(256)
void gemm_qkv(const unsigned short* __restrict__ xb,
              const unsigned short* __restrict__ cb,
              const unsigned short* __restrict__ wq,
              const unsigned short* __restrict__ wk,
              const unsigned short* __restrict__ wv,
              const float* __restrict__ bq, const float* __restrict__ bk,
              const float* __restrict__ bv,
              unsigned short* __restrict__ qh, unsigned short* __restrict__ kh,
              unsigned short* __restrict__ vt) {
  const int x = blockIdx.x, y = blockIdx.y;
  if (y < 8)
    gemm_body(cb, wk, bk, kh, x * 128, y * 128, 11, 1.f, 0);
  else if (y < 16)
    gemm_body(cb, wv, bv, vt, x * 128, (y - 8) * 128, 11, 1.f, 2);
  else
    gemm_body(xb, wq, bq, qh, (x & 15) * 128, (y - 16) * 512 + (x >> 4) * 128,
              9, QSC, 0);
}

// Output projection: fp32 out. Grid (16, 8).
__global__ __launch_bounds__(256)
void gemm_o(const unsigned short* __restrict__ ah,
            const unsigned short* __restrict__ wo,
            const float* __restrict__ bo, float* __restrict__ out) {
  gemm_body(ah, wo, bo, out, blockIdx.x * 128, blockIdx.y * 128, 0, 1.f, 1);
}

// ---------------------------------------------------------------------------
// Split-K flash attention, fixed-max softmax. Grid (64 bh, 8 qblk), block 256.
// Wave w covers keys {w*64 + 256t}, t=0..7; all waves share the block's 64 q
// rows; no barriers in the main loop. K-frags prefetched one tile ahead in
// registers (double-buffered via t-unroll-2). Scores arrive in log2 units
// (Wq pre-scaled by QSC); mask bias carries the fixed -8 max-shift.
// PS: p_lds row stride in u16. MUST be == 0 mod 8 (16 B) -- the P fragments
// are read as u16x8 (ds_read_b128); any other stride misaligns odd q-rows.
#define PS 72
__global__ __launch_bounds__(256, 2)
void attn_kernel(const unsigned short* __restrict__ Q,   // [64][512][64]
                 const unsigned short* __restrict__ K,   // [64][2048][64]
                 const unsigned short* __restrict__ Vt,  // [64][64][2048]
                 const int* __restrict__ mask,           // [4][2048]
                 unsigned short* __restrict__ O) {       // [4][512][1024]
  __shared__ float bias_lds[2048];
  __shared__ __align__(16) unsigned short p_lds[4][2][16 * PS];
  __shared__ float l_lds[4][64];
  __shared__ __align__(16) float o_comb[64][68];

  const int tid = threadIdx.x;
  const int wave = tid >> 6, lane = tid & 63;
  const int l15 = lane & 15, quad = lane >> 4;
  const int bh = blockIdx.x, b = bh >> 4, h = bh & 15;
  const int q0 = blockIdx.y * 64;

  {  // mask -> additive bias in log2 units, with fixed max-shift -8 folded in
    const int* mb = mask + b * 2048;
    for (int i = tid; i < 2048; i += 256)
      bias_lds[i] = mb[i] ? -8.f : -1e30f;
  }
  __syncthreads();

  const unsigned short* Qb = Q + ((size_t)bh * 512 + q0) * 64;
  const unsigned short* Kb = K + (size_t)bh * (2048 * 64);
  const unsigned short* Vb = Vt + (size_t)bh * (64 * 2048);

  // Q fragments: lane l15 = q row, elements = d. Held all kernel.
  u16x8 aq[4][2];
#pragma unroll
  for (int qg = 0; qg < 4; ++qg)
#pragma unroll
    for (int ks = 0; ks < 2; ++ks)
      aq[qg][ks] = *(const u16x8*)(Qb + (qg * 16 + l15) * 64 + ks * 32 + quad * 8);

  f32x4 o_acc[4][4] = {};
  float l_s[4] = {0.f, 0.f, 0.f, 0.f};

  u16x8 kfA[2][4], kfB[2][4];

  auto load_k = [&](u16x8 (&kf)[2][4], int kb) {
#pragma unroll
    for (int ns = 0; ns < 4; ++ns)
#pragma unroll
      for (int ks = 0; ks < 2; ++ks)
        kf[ks][ns] = *(const u16x8*)(Kb + (size_t)(kb + ns * 16 + l15) * 64 + ks * 32 + quad * 8);
  };

  auto do_tile = [&](u16x8 (&kf)[2][4], int kb) {
    // V^T frags (B-op: lane=d, elems=key): consumed only after S+softmax,
    // so these loads have ~250cy of slack from issue to first use.
    u16x8 vf[2][4];
#pragma unroll
    for (int nd = 0; nd < 4; ++nd)
#pragma unroll
      for (int ks = 0; ks < 2; ++ks)
        vf[ks][nd] = *(const u16x8*)(Vb + (size_t)(nd * 16 + l15) * 2048 + kb + ks * 32 + quad * 8);
    f32x4 bfr[4];
#pragma unroll
    for (int ns = 0; ns < 4; ++ns)
      bfr[ns] = *(const f32x4*)&bias_lds[kb + ns * 16 + quad * 4];

#pragma unroll
    for (int qg = 0; qg < 4; ++qg) {
      // S^T tile: D[key = ns*16+quad*4+r][q = l15], C-init = bias (-8 shift)
      f32x4 sfr[4];
#pragma unroll
      for (int ns = 0; ns < 4; ++ns) {
        f32x4 sa = bfr[ns];
#pragma unroll
        for (int ks = 0; ks < 2; ++ks)
          sa = mfma16(kf[ks][ns], aq[qg][ks], sa);
        sfr[ns] = sa;
      }

      float rsum = 0.f;
#pragma unroll
      for (int ns = 0; ns < 4; ++ns) {
        unsigned int pr[4];
#pragma unroll
        for (int r = 0; r < 4; ++r) {
          float p = exp2_fast(sfr[ns][r]);
          unsigned int u = __builtin_bit_cast(unsigned int, p) & 0xffff0000u;
          rsum += __builtin_bit_cast(float, u);  // sum TRUNCATED p: consistent with PV
          pr[r] = u;
        }
        uint2 pw;
        pw.x = __builtin_amdgcn_perm(pr[1], pr[0], 0x07060302u);
        pw.y = __builtin_amdgcn_perm(pr[3], pr[2], 0x07060302u);
        *(uint2*)&p_lds[wave][qg & 1][l15 * PS + ns * 16 + quad * 4] = pw;
      }
      rsum += __shfl_xor(rsum, 16, 64);
      rsum += __shfl_xor(rsum, 32, 64);
      l_s[qg] += rsum;

      // PV: A = P (lane=q, elems=key) from p_lds; B = V^T frags
#pragma unroll
      for (int ks = 0; ks < 2; ++ks) {
        u16x8 pf = *(const u16x8*)&p_lds[wave][qg & 1][l15 * PS + ks * 32 + quad * 8];
#pragma unroll
        for (int nd = 0; nd < 4; ++nd)
          o_acc[qg][nd] = mfma16(pf, vf[ks][nd], o_acc[qg][nd]);
      }
    }
  };

  load_k(kfA, wave * 64);
#pragma unroll 1
  for (int t = 0; t < 8; t += 2) {
    const int kb0 = wave * 64 + t * 256;
    load_k(kfB, kb0 + 256);            // prefetch t+1 (in flight during compute)
    do_tile(kfA, kb0);
    if (t + 2 < 8) load_k(kfA, kb0 + 512);  // prefetch t+2
    do_tile(kfB, kb0 + 256);
  }

  // ---- combine the 4 waves' partial (l, o): plain sums (fixed max) ----
  if (quad == 0) {
#pragma unroll
    for (int qg = 0; qg < 4; ++qg)
      l_lds[wave][qg * 16 + l15] = l_s[qg];
  }
  __syncthreads();

  for (int w = 0; w < 4; ++w) {
    if (wave == w) {
#pragma unroll
      for (int qg = 0; qg < 4; ++qg)
#pragma unroll
        for (int r = 0; r < 4; ++r) {
          const int q = qg * 16 + quad * 4 + r;
#pragma unroll
          for (int nd = 0; nd < 4; ++nd) {
            const int d = nd * 16 + l15;
            float v = o_acc[qg][nd][r];
            if (w == 0) o_comb[q][d] = v;
            else        o_comb[q][d] += v;
          }
        }
    }
    __syncthreads();
  }

  // ---- final normalize + store (two u16x8 per thread) ----
  {
    const int q = tid >> 2, dc = (tid & 3) * 16;
    const float inv = 1.f / (l_lds[0][q] + l_lds[1][q] + l_lds[2][q] + l_lds[3][q]);
    unsigned short* Ob = O + ((size_t)(b * 512 + q0 + q)) * 1024 + h * 64 + dc;
    u16x8 o1, o2;
#pragma unroll
    for (int j = 0; j < 8; ++j) o1[j] = f2bf(o_comb[q][dc + j] * inv);
#pragma unroll
    for (int j = 0; j < 8; ++j) o2[j] = f2bf(o_comb[q][dc + 8 + j] * inv);
    *(u16x8*)(Ob) = o1;
    *(u16x8*)(Ob + 8) = o2;
  }
}

// ---------------------------------------------------------------------------
extern "C" void kernel_launch(void* const* d_in, const int* in_sizes, int n_in,
                              void* d_out, int out_size, void* d_ws, size_t ws_size,
                              hipStream_t stream) {
  const float* x   = (const float*)d_in[0];
  const float* ctx = (const float*)d_in[1];
  const int* mask  = (const int*)d_in[2];
  const float* Wq  = (const float*)d_in[3];
  const float* bq  = (const float*)d_in[4];
  const float* Wk  = (const float*)d_in[5];
  const float* bk  = (const float*)d_in[6];
  const float* Wv  = (const float*)d_in[7];
  const float* bv  = (const float*)d_in[8];
  const float* Wo  = (const float*)d_in[9];
  const float* bo  = (const float*)d_in[10];

  char* ws = (char*)d_ws;
  // [MB] xb 0-4, cb 4-20, w 20-28, qh 28-32, kh 32-48, vt 48-64, ah 64-68.
  unsigned short* xb  = (unsigned short*)(ws + ((size_t)0  << 20));
  unsigned short* cb  = (unsigned short*)(ws + ((size_t)4  << 20));
  unsigned short* wqb = (unsigned short*)(ws + ((size_t)20 << 20));
  unsigned short* wkb = (unsigned short*)(ws + ((size_t)22 << 20));
  unsigned short* wvb = (unsigned short*)(ws + ((size_t)24 << 20));
  unsigned short* wob = (unsigned short*)(ws + ((size_t)26 << 20));
  unsigned short* qh  = (unsigned short*)(ws + ((size_t)28 << 20));
  unsigned short* kh  = (unsigned short*)(ws + ((size_t)32 << 20));
  unsigned short* vt  = (unsigned short*)(ws + ((size_t)48 << 20));
  unsigned short* ah  = (unsigned short*)(ws + ((size_t)64 << 20));

  cast_fused<<<14336, 256, 0, stream>>>(x, ctx, Wq, Wk, Wv, Wo,
                                        xb, cb, wqb, wkb, wvb, wob);
  gemm_qkv<<<dim3(64, 18), 256, 0, stream>>>(xb, cb, wqb, wkb, wvb,
                                             bq, bk, bv, qh, kh, vt);
  attn_kernel<<<dim3(64, 8), 256, 0, stream>>>(qh, kh, vt, mask, ah);
  gemm_o<<<dim3(16, 8), 256, 0, stream>>>(ah, wob, bo, (float*)d_out);
}

// Round 6
// 233.817 us; speedup vs baseline: 1.1788x; 1.0966x over previous
//
#include <hip/hip_runtime.h>
#include <hip/hip_bf16.h>
#include <stdint.h>

// ---------------------------------------------------------------------------
// CrossAttention B=4 N=512 M=2048 C=1024 H=16 D=64, bf16 MFMA fp32 accum.
// R6: attn register-pressure fix -- single K-fragment buffer with
// post-last-use prefetch (R5 double-buffer put the kernel at ~260 VGPR vs the
// 256 cap from launch_bounds(256,2) => scratch spills, 4x write amplification
// seen in counters). gemm_o re-tiled 64x128 -> 256 blocks (was 128 on 256 CUs).
// ---------------------------------------------------------------------------

typedef __attribute__((ext_vector_type(4))) float f32x4;
typedef __attribute__((ext_vector_type(8))) __bf16 bf16x8;
typedef __attribute__((ext_vector_type(8))) unsigned short u16x8;

#define DEVI __device__ __forceinline__

// SCALE * log2(e): folded into Wq cast so QK^T scores land in log2 units.
#define QSC (0.125f * 1.44269504088896f)

DEVI f32x4 mfma16(u16x8 a, u16x8 b, f32x4 c) {
  return __builtin_amdgcn_mfma_f32_16x16x32_bf16(
      __builtin_bit_cast(bf16x8, a), __builtin_bit_cast(bf16x8, b), c, 0, 0, 0);
}

// round-to-nearest-even fp32 -> bf16
DEVI unsigned short f2bf(float f) {
  union { float f; unsigned int u; } x; x.f = f;
  unsigned int u = x.u;
  return (unsigned short)((u + 0x7fffu + ((u >> 16) & 1u)) >> 16);
}

DEVI float exp2_fast(float x) {
#if __has_builtin(__builtin_amdgcn_exp2f)
  return __builtin_amdgcn_exp2f(x);
#else
  return exp2f(x);
#endif
}

// async global->LDS, 16 bytes per lane (global_load_lds_dwordx4)
DEVI void llds16(const void* g, void* l) {
  __builtin_amdgcn_global_load_lds(
      (const __attribute__((address_space(1))) void*)g,
      (__attribute__((address_space(3))) void*)l, 16, 0, 0);
}

// ---------------------------------------------------------------------------
// One kernel casts all six fp32 inputs to bf16. Wq gets QSC folded in.
__global__ __launch_bounds__(256)
void cast_fused(const float* __restrict__ x, const float* __restrict__ ctx,
                const float* __restrict__ wq, const float* __restrict__ wk,
                const float* __restrict__ wv, const float* __restrict__ wo,
                unsigned short* __restrict__ xb, unsigned short* __restrict__ cb,
                unsigned short* __restrict__ wqb, unsigned short* __restrict__ wkb,
                unsigned short* __restrict__ wvb, unsigned short* __restrict__ wob) {
  int bid = blockIdx.x;
  const float* src; unsigned short* dst; float scale = 1.f;
  if (bid < 2048)        { src = x;   dst = xb; }
  else if (bid < 10240)  { src = ctx; dst = cb;  bid -= 2048; }
  else if (bid < 11264)  { src = wq;  dst = wqb; bid -= 10240; scale = QSC; }
  else if (bid < 12288)  { src = wk;  dst = wkb; bid -= 11264; }
  else if (bid < 13312)  { src = wv;  dst = wvb; bid -= 12288; }
  else                   { src = wo;  dst = wob; bid -= 13312; }
  int idx = (bid * 256 + threadIdx.x) * 4;
  const float4 v = *(const float4*)(src + idx);
  ushort4 o;
  o.x = f2bf(v.x * scale); o.y = f2bf(v.y * scale);
  o.z = f2bf(v.z * scale); o.w = f2bf(v.w * scale);
  *(ushort4*)(dst + idx) = o;
}

// ---------------------------------------------------------------------------
// GEMM body: C = A[.,1024] @ W[1024,1024]^T + bias*bscale. 128x128 tile, BK=64.
// mode 0: bf16 out permuted to [B,H,S,64] (S = 1<<logS), LDS-staged epilogue.
// mode 2: bf16 out transposed to [B*16+h][d][m] (V^T), LDS-staged epilogue.
DEVI void gemm_body(const unsigned short* __restrict__ A,
                    const unsigned short* __restrict__ W,
                    const float* __restrict__ bias,
                    void* __restrict__ Cout,
                    int bm, int bn, int logS, float bscale, int mode) {
  constexpr int K = 1024;
  __shared__ __align__(16) unsigned short sh[128 * 64 * 2];  // As | Bs, then C-stage
  unsigned short* As = sh;
  unsigned short* Bs = sh + 128 * 64;

  const int tid = threadIdx.x;
  const int wave = tid >> 6, lane = tid & 63;
  const int l15 = lane & 15, quad = lane >> 4;
  const int wm = wave & 1, wn = wave >> 1;

  f32x4 acc[4][4] = {};

  for (int k0 = 0; k0 < K; k0 += 64) {
    __syncthreads();
#pragma unroll
    for (int c = 0; c < 4; ++c) {
      int s = c * 256 + tid;
      int m = s >> 3;
      int k8 = (s & 7) ^ (m & 7);
      llds16(A + (size_t)(bm + m) * K + k0 + k8 * 8, &As[s * 8]);
      llds16(W + (size_t)(bn + m) * K + k0 + k8 * 8, &Bs[s * 8]);
    }
    __syncthreads();
#pragma unroll
    for (int ks = 0; ks < 2; ++ks) {
      u16x8 af[4], bf[4];
      const int k8 = ks * 4 + quad;
#pragma unroll
      for (int i = 0; i < 4; ++i) {
        int m = wm * 64 + i * 16 + l15;
        af[i] = *(const u16x8*)(&As[(m * 8 + (k8 ^ (m & 7))) * 8]);
        int n = wn * 64 + i * 16 + l15;
        bf[i] = *(const u16x8*)(&Bs[(n * 8 + (k8 ^ (n & 7))) * 8]);
      }
#pragma unroll
      for (int mi = 0; mi < 4; ++mi)
#pragma unroll
        for (int ni = 0; ni < 4; ++ni)
          acc[mi][ni] = mfma16(af[mi], bf[ni], acc[mi][ni]);
    }
  }

  // bf16 epilogues via LDS, two 64-row phases (reuse sh as C-stage)
  unsigned short* cst = sh;
  __syncthreads();
  for (int half = 0; half < 2; ++half) {
    if (wm == half) {
#pragma unroll
      for (int mi = 0; mi < 4; ++mi)
#pragma unroll
        for (int ni = 0; ni < 4; ++ni)
#pragma unroll
          for (int r = 0; r < 4; ++r) {
            int lrow = mi * 16 + quad * 4 + r;          // 0..63
            int lcol = wn * 64 + ni * 16 + l15;         // 0..127
            int col = bn + lcol;
            unsigned short bv = f2bf(acc[mi][ni][r] + bias[col] * bscale);
            if (mode == 0) cst[lrow * 136 + lcol] = bv;
            else           cst[lcol * 72 + lrow] = bv;  // transposed
          }
    }
    __syncthreads();
    if (mode == 0) {
      // [B,H,S,64]: coalesced u16x8 along d
      int lrow = tid >> 2, cc = (tid & 3) * 32;
      int row = bm + half * 64 + lrow;
      int b = row >> logS, sl = row & ((1 << logS) - 1);
#pragma unroll
      for (int j = 0; j < 4; ++j) {
        int col = bn + cc + j * 8;
        int h = col >> 6, d = col & 63;
        *(u16x8*)&((unsigned short*)Cout)[(((size_t)(b * 16 + h) << logS) + sl) * 64 + d] =
            *(const u16x8*)&cst[lrow * 136 + cc + j * 8];
      }
    } else {
      // V^T [bh][d][2048]: coalesced u16x8 along m
      int c = tid >> 1, rc = (tid & 1) * 32;
      int gc = bn + c, h = gc >> 6, d = gc & 63;
      int b = bm >> 11;
      size_t base = ((size_t)(b * 16 + h) * 64 + d) * 2048 + (bm & 2047) + half * 64 + rc;
#pragma unroll
      for (int j = 0; j < 4; ++j)
        *(u16x8*)&((unsigned short*)Cout)[base + j * 8] =
            *(const u16x8*)&cst[c * 72 + rc + j * 8];
    }
    __syncthreads();
  }
}

// Fused Q/K/V projection. Grid (64, 18).
__global__ __launch_bounds__(256)
void gemm_qkv(const unsigned short* __restrict__ xb,
              const unsigned short* __restrict__ cb,
              const unsigned short* __restrict__ wq,
              const unsigned short* __restrict__ wk,
              const unsigned short* __restrict__ wv,
              const float* __restrict__ bq, const float* __restrict__ bk,
              const float* __restrict__ bv,
              unsigned short* __restrict__ qh, unsigned short* __restrict__ kh,
              unsigned short* __restrict__ vt) {
  const int x = blockIdx.x, y = blockIdx.y;
  if (y < 8)
    gemm_body(cb, wk, bk, kh, x * 128, y * 128, 11, 1.f, 0);
  else if (y < 16)
    gemm_body(cb, wv, bv, vt, x * 128, (y - 8) * 128, 11, 1.f, 2);
  else
    gemm_body(xb, wq, bq, qh, (x & 15) * 128, (y - 16) * 512 + (x >> 4) * 128,
              9, QSC, 0);
}

// ---------------------------------------------------------------------------
// Output projection: out[2048,1024] fp32 = ah @ Wo^T + bo. 64x128 tile,
// grid (32, 8) = 256 blocks (one per CU), 4 waves each 64 rows x 32 cols.
__global__ __launch_bounds__(256)
void gemm_o(const unsigned short* __restrict__ A,
            const unsigned short* __restrict__ W,
            const float* __restrict__ bo, float* __restrict__ out) {
  constexpr int K = 1024;
  __shared__ __align__(16) unsigned short As[64 * 64];   // 8 KB
  __shared__ __align__(16) unsigned short Bs[128 * 64];  // 16 KB

  const int tid = threadIdx.x;
  const int wave = tid >> 6, lane = tid & 63;
  const int l15 = lane & 15, quad = lane >> 4;
  const int bm = blockIdx.x * 64, bn = blockIdx.y * 128;

  f32x4 acc[4][2] = {};

  for (int k0 = 0; k0 < K; k0 += 64) {
    __syncthreads();
#pragma unroll
    for (int c = 0; c < 2; ++c) {
      int s = c * 256 + tid;
      int m = s >> 3, k8 = (s & 7) ^ (m & 7);
      llds16(A + (size_t)(bm + m) * K + k0 + k8 * 8, &As[s * 8]);
    }
#pragma unroll
    for (int c = 0; c < 4; ++c) {
      int s = c * 256 + tid;
      int m = s >> 3, k8 = (s & 7) ^ (m & 7);
      llds16(W + (size_t)(bn + m) * K + k0 + k8 * 8, &Bs[s * 8]);
    }
    __syncthreads();
#pragma unroll
    for (int ks = 0; ks < 2; ++ks) {
      const int k8 = ks * 4 + quad;
      u16x8 af[4], bf[2];
#pragma unroll
      for (int i = 0; i < 4; ++i) {
        int m = i * 16 + l15;
        af[i] = *(const u16x8*)(&As[(m * 8 + (k8 ^ (m & 7))) * 8]);
      }
#pragma unroll
      for (int i = 0; i < 2; ++i) {
        int n = wave * 32 + i * 16 + l15;
        bf[i] = *(const u16x8*)(&Bs[(n * 8 + (k8 ^ (n & 7))) * 8]);
      }
#pragma unroll
      for (int mi = 0; mi < 4; ++mi)
#pragma unroll
        for (int ni = 0; ni < 2; ++ni)
          acc[mi][ni] = mfma16(af[mi], bf[ni], acc[mi][ni]);
    }
  }

#pragma unroll
  for (int mi = 0; mi < 4; ++mi)
#pragma unroll
    for (int ni = 0; ni < 2; ++ni)
#pragma unroll
      for (int r = 0; r < 4; ++r) {
        int row = bm + mi * 16 + quad * 4 + r;
        int col = bn + wave * 32 + ni * 16 + l15;
        out[(size_t)row * 1024 + col] = acc[mi][ni][r] + bo[col];
      }
}

// ---------------------------------------------------------------------------
// Split-K flash attention, fixed-max softmax. Grid (64 bh, 8 qblk), block 256.
// Wave w covers keys {w*64 + 256t}, t=0..7; no barriers in the main loop.
// SINGLE K-fragment buffer: kf(t+1) loads issue right after kf's last use
// (qg==3's S-MFMA), covered by softmax+PV (~450 cy). vf(t) loads at tile
// start, covered by S+softmax of qg0 (~400 cy). Keeps peak VGPR ~230 < 256
// (R5's double-buffer spilled to scratch: 4x write amplification).
// PS: p_lds row stride in u16. MUST be == 0 mod 8 (16 B) -- P fragments are
// read as u16x8 (ds_read_b128); any other stride misaligns odd q-rows.
#define PS 72
__global__ __launch_bounds__(256, 2)
void attn_kernel(const unsigned short* __restrict__ Q,   // [64][512][64]
                 const unsigned short* __restrict__ K,   // [64][2048][64]
                 const unsigned short* __restrict__ Vt,  // [64][64][2048]
                 const int* __restrict__ mask,           // [4][2048]
                 unsigned short* __restrict__ O) {       // [4][512][1024]
  __shared__ float bias_lds[2048];
  __shared__ __align__(16) unsigned short p_lds[4][2][16 * PS];
  __shared__ float l_lds[4][64];
  __shared__ __align__(16) float o_comb[64][68];

  const int tid = threadIdx.x;
  const int wave = tid >> 6, lane = tid & 63;
  const int l15 = lane & 15, quad = lane >> 4;
  const int bh = blockIdx.x, b = bh >> 4, h = bh & 15;
  const int q0 = blockIdx.y * 64;

  {  // mask -> additive bias in log2 units, with fixed max-shift -8 folded in
    const int* mb = mask + b * 2048;
    for (int i = tid; i < 2048; i += 256)
      bias_lds[i] = mb[i] ? -8.f : -1e30f;
  }
  __syncthreads();

  const unsigned short* Qb = Q + ((size_t)bh * 512 + q0) * 64;
  const unsigned short* Kb = K + (size_t)bh * (2048 * 64);
  const unsigned short* Vb = Vt + (size_t)bh * (64 * 2048);

  // Q fragments: lane l15 = q row, elements = d. Held all kernel.
  u16x8 aq[4][2];
#pragma unroll
  for (int qg = 0; qg < 4; ++qg)
#pragma unroll
    for (int ks = 0; ks < 2; ++ks)
      aq[qg][ks] = *(const u16x8*)(Qb + (qg * 16 + l15) * 64 + ks * 32 + quad * 8);

  f32x4 o_acc[4][4] = {};
  float l_s[4] = {0.f, 0.f, 0.f, 0.f};

  u16x8 kf[2][4];

  auto load_k = [&](int kb) {
#pragma unroll
    for (int ns = 0; ns < 4; ++ns)
#pragma unroll
      for (int ks = 0; ks < 2; ++ks)
        kf[ks][ns] = *(const u16x8*)(Kb + (size_t)(kb + ns * 16 + l15) * 64 + ks * 32 + quad * 8);
  };

  load_k(wave * 64);

#pragma unroll 1
  for (int t = 0; t < 8; ++t) {
    const int kb = wave * 64 + t * 256;
    const int kb_next = kb + (t < 7 ? 256 : 0);

    // V^T frags (B-op: lane=d, elems=key): consumed in PV, first use is
    // ~400 cy after issue (S + softmax of qg0).
    u16x8 vf[2][4];
#pragma unroll
    for (int nd = 0; nd < 4; ++nd)
#pragma unroll
      for (int ks = 0; ks < 2; ++ks)
        vf[ks][nd] = *(const u16x8*)(Vb + (size_t)(nd * 16 + l15) * 2048 + kb + ks * 32 + quad * 8);
    f32x4 bfr[4];
#pragma unroll
    for (int ns = 0; ns < 4; ++ns)
      bfr[ns] = *(const f32x4*)&bias_lds[kb + ns * 16 + quad * 4];

#pragma unroll
    for (int qg = 0; qg < 4; ++qg) {
      // S^T tile: D[key = ns*16+quad*4+r][q = l15], C-init = bias (-8 shift)
      f32x4 sfr[4];
#pragma unroll
      for (int ns = 0; ns < 4; ++ns) {
        f32x4 sa = bfr[ns];
#pragma unroll
        for (int ks = 0; ks < 2; ++ks)
          sa = mfma16(kf[ks][ns], aq[qg][ks], sa);
        sfr[ns] = sa;
      }

      // kf dead after qg==3's S: reload for next tile now (covered by the
      // remaining softmax + PV of this qg).
      if (qg == 3) load_k(kb_next);

      float rsum = 0.f;
#pragma unroll
      for (int ns = 0; ns < 4; ++ns) {
        unsigned int pr[4];
#pragma unroll
        for (int r = 0; r < 4; ++r) {
          float p = exp2_fast(sfr[ns][r]);
          unsigned int u = __builtin_bit_cast(unsigned int, p) & 0xffff0000u;
          rsum += __builtin_bit_cast(float, u);  // sum TRUNCATED p: consistent with PV
          pr[r] = u;
        }
        uint2 pw;
        pw.x = __builtin_amdgcn_perm(pr[1], pr[0], 0x07060302u);
        pw.y = __builtin_amdgcn_perm(pr[3], pr[2], 0x07060302u);
        *(uint2*)&p_lds[wave][qg & 1][l15 * PS + ns * 16 + quad * 4] = pw;
      }
      rsum += __shfl_xor(rsum, 16, 64);
      rsum += __shfl_xor(rsum, 32, 64);
      l_s[qg] += rsum;

      // PV: A = P (lane=q, elems=key) from p_lds; B = V^T frags
#pragma unroll
      for (int ks = 0; ks < 2; ++ks) {
        u16x8 pf = *(const u16x8*)&p_lds[wave][qg & 1][l15 * PS + ks * 32 + quad * 8];
#pragma unroll
        for (int nd = 0; nd < 4; ++nd)
          o_acc[qg][nd] = mfma16(pf, vf[ks][nd], o_acc[qg][nd]);
      }
    }
  }

  // ---- combine the 4 waves' partial (l, o): plain sums (fixed max) ----
  if (quad == 0) {
#pragma unroll
    for (int qg = 0; qg < 4; ++qg)
      l_lds[wave][qg * 16 + l15] = l_s[qg];
  }
  __syncthreads();

  for (int w = 0; w < 4; ++w) {
    if (wave == w) {
#pragma unroll
      for (int qg = 0; qg < 4; ++qg)
#pragma unroll
        for (int r = 0; r < 4; ++r) {
          const int q = qg * 16 + quad * 4 + r;
#pragma unroll
          for (int nd = 0; nd < 4; ++nd) {
            const int d = nd * 16 + l15;
            float v = o_acc[qg][nd][r];
            if (w == 0) o_comb[q][d] = v;
            else        o_comb[q][d] += v;
          }
        }
    }
    __syncthreads();
  }

  // ---- final normalize + store (two u16x8 per thread) ----
  {
    const int q = tid >> 2, dc = (tid & 3) * 16;
    const float inv = 1.f / (l_lds[0][q] + l_lds[1][q] + l_lds[2][q] + l_lds[3][q]);
    unsigned short* Ob = O + ((size_t)(b * 512 + q0 + q)) * 1024 + h * 64 + dc;
    u16x8 o1, o2;
#pragma unroll
    for (int j = 0; j < 8; ++j) o1[j] = f2bf(o_comb[q][dc + j] * inv);
#pragma unroll
    for (int j = 0; j < 8; ++j) o2[j] = f2bf(o_comb[q][dc + 8 + j] * inv);
    *(u16x8*)(Ob) = o1;
    *(u16x8*)(Ob + 8) = o2;
  }
}

// ---------------------------------------------------------------------------
extern "C" void kernel_launch(void* const* d_in, const int* in_sizes, int n_in,
                              void* d_out, int out_size, void* d_ws, size_t ws_size,
                              hipStream_t stream) {
  const float* x   = (const float*)d_in[0];
  const float* ctx = (const float*)d_in[1];
  const int* mask  = (const int*)d_in[2];
  const float* Wq  = (const float*)d_in[3];
  const float* bq  = (const float*)d_in[4];
  const float* Wk  = (const float*)d_in[5];
  const float* bk  = (const float*)d_in[6];
  const float* Wv  = (const float*)d_in[7];
  const float* bv  = (const float*)d_in[8];
  const float* Wo  = (const float*)d_in[9];
  const float* bo  = (const float*)d_in[10];

  char* ws = (char*)d_ws;
  // [MB] xb 0-4, cb 4-20, w 20-28, qh 28-32, kh 32-48, vt 48-64, ah 64-68.
  unsigned short* xb  = (unsigned short*)(ws + ((size_t)0  << 20));
  unsigned short* cb  = (unsigned short*)(ws + ((size_t)4  << 20));
  unsigned short* wqb = (unsigned short*)(ws + ((size_t)20 << 20));
  unsigned short* wkb = (unsigned short*)(ws + ((size_t)22 << 20));
  unsigned short* wvb = (unsigned short*)(ws + ((size_t)24 << 20));
  unsigned short* wob = (unsigned short*)(ws + ((size_t)26 << 20));
  unsigned short* qh  = (unsigned short*)(ws + ((size_t)28 << 20));
  unsigned short* kh  = (unsigned short*)(ws + ((size_t)32 << 20));
  unsigned short* vt  = (unsigned short*)(ws + ((size_t)48 << 20));
  unsigned short* ah  = (unsigned short*)(ws + ((size_t)64 << 20));

  cast_fused<<<14336, 256, 0, stream>>>(x, ctx, Wq, Wk, Wv, Wo,
                                        xb, cb, wqb, wkb, wvb, wob);
  gemm_qkv<<<dim3(64, 18), 256, 0, stream>>>(xb, cb, wqb, wkb, wvb,
                                             bq, bk, bv, qh, kh, vt);
  attn_kernel<<<dim3(64, 8), 256, 0, stream>>>(qh, kh, vt, mask, ah);
  gemm_o<<<dim3(32, 8), 256, 0, stream>>>(ah, wob, bo, (float*)d_out);
}

// Round 7
// 215.212 us; speedup vs baseline: 1.2807x; 1.0865x over previous
//
#include <hip/hip_runtime.h>
#include <hip/hip_bf16.h>
#include <stdint.h>

// ---------------------------------------------------------------------------
// CrossAttention B=4 N=512 M=2048 C=1024 H=16 D=64, bf16 MFMA fp32 accum.
// R7: K+V projection fused per block -- K and V GEMMs share the A matrix
// (ctx), so one block stages the A-tile once and runs both weight tiles:
// 48 KB staged per 64 MFMA (was 32 KB per 32) => 2x MFMA per barrier pair,
// -25% staging bytes per MFMA. VGPR audit ~190 < 256 (launch_bounds(256,2)).
// ---------------------------------------------------------------------------

typedef __attribute__((ext_vector_type(4))) float f32x4;
typedef __attribute__((ext_vector_type(8))) __bf16 bf16x8;
typedef __attribute__((ext_vector_type(8))) unsigned short u16x8;

#define DEVI __device__ __forceinline__

// SCALE * log2(e): folded into Wq cast so QK^T scores land in log2 units.
#define QSC (0.125f * 1.44269504088896f)

DEVI f32x4 mfma16(u16x8 a, u16x8 b, f32x4 c) {
  return __builtin_amdgcn_mfma_f32_16x16x32_bf16(
      __builtin_bit_cast(bf16x8, a), __builtin_bit_cast(bf16x8, b), c, 0, 0, 0);
}

// round-to-nearest-even fp32 -> bf16
DEVI unsigned short f2bf(float f) {
  union { float f; unsigned int u; } x; x.f = f;
  unsigned int u = x.u;
  return (unsigned short)((u + 0x7fffu + ((u >> 16) & 1u)) >> 16);
}

DEVI float exp2_fast(float x) {
#if __has_builtin(__builtin_amdgcn_exp2f)
  return __builtin_amdgcn_exp2f(x);
#else
  return exp2f(x);
#endif
}

// async global->LDS, 16 bytes per lane (global_load_lds_dwordx4)
DEVI void llds16(const void* g, void* l) {
  __builtin_amdgcn_global_load_lds(
      (const __attribute__((address_space(1))) void*)g,
      (__attribute__((address_space(3))) void*)l, 16, 0, 0);
}

// ---------------------------------------------------------------------------
// One kernel casts all six fp32 inputs to bf16. Wq gets QSC folded in.
__global__ __launch_bounds__(256)
void cast_fused(const float* __restrict__ x, const float* __restrict__ ctx,
                const float* __restrict__ wq, const float* __restrict__ wk,
                const float* __restrict__ wv, const float* __restrict__ wo,
                unsigned short* __restrict__ xb, unsigned short* __restrict__ cb,
                unsigned short* __restrict__ wqb, unsigned short* __restrict__ wkb,
                unsigned short* __restrict__ wvb, unsigned short* __restrict__ wob) {
  int bid = blockIdx.x;
  const float* src; unsigned short* dst; float scale = 1.f;
  if (bid < 2048)        { src = x;   dst = xb; }
  else if (bid < 10240)  { src = ctx; dst = cb;  bid -= 2048; }
  else if (bid < 11264)  { src = wq;  dst = wqb; bid -= 10240; scale = QSC; }
  else if (bid < 12288)  { src = wk;  dst = wkb; bid -= 11264; }
  else if (bid < 13312)  { src = wv;  dst = wvb; bid -= 12288; }
  else                   { src = wo;  dst = wob; bid -= 13312; }
  int idx = (bid * 256 + threadIdx.x) * 4;
  const float4 v = *(const float4*)(src + idx);
  ushort4 o;
  o.x = f2bf(v.x * scale); o.y = f2bf(v.y * scale);
  o.z = f2bf(v.z * scale); o.w = f2bf(v.w * scale);
  *(ushort4*)(dst + idx) = o;
}

// ---------------------------------------------------------------------------
// Epilogue helpers: stage a 128x128 bf16 C tile through LDS, store coalesced.
// mode 0: [B,H,S,64] permute (S = 1<<logS). mode 2: V^T [bh][d][2048].
DEVI void epi_store(f32x4 (&acc)[4][4], const float* __restrict__ bias,
                    float bscale, void* __restrict__ Cout,
                    int bm, int bn, int logS, int mode,
                    unsigned short* cst, int tid, int wave, int l15, int quad) {
  const int wm = wave & 1, wn = wave >> 1;
  __syncthreads();
  for (int half = 0; half < 2; ++half) {
    if (wm == half) {
#pragma unroll
      for (int mi = 0; mi < 4; ++mi)
#pragma unroll
        for (int ni = 0; ni < 4; ++ni)
#pragma unroll
          for (int r = 0; r < 4; ++r) {
            int lrow = mi * 16 + quad * 4 + r;          // 0..63
            int lcol = wn * 64 + ni * 16 + l15;         // 0..127
            unsigned short bv = f2bf(acc[mi][ni][r] + bias[bn + lcol] * bscale);
            if (mode == 0) cst[lrow * 136 + lcol] = bv;
            else           cst[lcol * 72 + lrow] = bv;  // transposed
          }
    }
    __syncthreads();
    if (mode == 0) {
      int lrow = tid >> 2, cc = (tid & 3) * 32;
      int row = bm + half * 64 + lrow;
      int b = row >> logS, sl = row & ((1 << logS) - 1);
#pragma unroll
      for (int j = 0; j < 4; ++j) {
        int col = bn + cc + j * 8;
        int h = col >> 6, d = col & 63;
        *(u16x8*)&((unsigned short*)Cout)[(((size_t)(b * 16 + h) << logS) + sl) * 64 + d] =
            *(const u16x8*)&cst[lrow * 136 + cc + j * 8];
      }
    } else {
      int c = tid >> 1, rc = (tid & 1) * 32;
      int gc = bn + c, h = gc >> 6, d = gc & 63;
      int b = bm >> 11;
      size_t base = ((size_t)(b * 16 + h) * 64 + d) * 2048 + (bm & 2047) + half * 64 + rc;
#pragma unroll
      for (int j = 0; j < 4; ++j)
        *(u16x8*)&((unsigned short*)Cout)[base + j * 8] =
            *(const u16x8*)&cst[c * 72 + rc + j * 8];
    }
    __syncthreads();
  }
}

// ---------------------------------------------------------------------------
// Fused K+V body: both GEMMs read the same A rows; stage A once per K-step,
// run Wk and Wv tiles against it. 64 MFMA per barrier pair.
DEVI void kv_body(const unsigned short* __restrict__ A,
                  const unsigned short* __restrict__ WK,
                  const unsigned short* __restrict__ WV,
                  const float* __restrict__ bk, const float* __restrict__ bv,
                  unsigned short* __restrict__ kh, unsigned short* __restrict__ vt,
                  int bm, int bn, unsigned short* sh) {
  constexpr int K = 1024;
  unsigned short* As = sh;
  unsigned short* Ks = sh + 128 * 64;
  unsigned short* Vs = sh + 2 * 128 * 64;

  const int tid = threadIdx.x;
  const int wave = tid >> 6, lane = tid & 63;
  const int l15 = lane & 15, quad = lane >> 4;
  const int wm = wave & 1, wn = wave >> 1;

  f32x4 ak[4][4] = {}, av[4][4] = {};

  for (int k0 = 0; k0 < K; k0 += 64) {
    __syncthreads();
#pragma unroll
    for (int c = 0; c < 4; ++c) {
      int s = c * 256 + tid;
      int m = s >> 3;
      int k8 = (s & 7) ^ (m & 7);
      llds16(A + (size_t)(bm + m) * K + k0 + k8 * 8, &As[s * 8]);
      llds16(WK + (size_t)(bn + m) * K + k0 + k8 * 8, &Ks[s * 8]);
      llds16(WV + (size_t)(bn + m) * K + k0 + k8 * 8, &Vs[s * 8]);
    }
    __syncthreads();
#pragma unroll
    for (int ks = 0; ks < 2; ++ks) {
      const int k8 = ks * 4 + quad;
      u16x8 af[4], bf[4];
#pragma unroll
      for (int i = 0; i < 4; ++i) {
        int m = wm * 64 + i * 16 + l15;
        af[i] = *(const u16x8*)(&As[(m * 8 + (k8 ^ (m & 7))) * 8]);
      }
#pragma unroll
      for (int i = 0; i < 4; ++i) {
        int n = wn * 64 + i * 16 + l15;
        bf[i] = *(const u16x8*)(&Ks[(n * 8 + (k8 ^ (n & 7))) * 8]);
      }
#pragma unroll
      for (int mi = 0; mi < 4; ++mi)
#pragma unroll
        for (int ni = 0; ni < 4; ++ni)
          ak[mi][ni] = mfma16(af[mi], bf[ni], ak[mi][ni]);
#pragma unroll
      for (int i = 0; i < 4; ++i) {
        int n = wn * 64 + i * 16 + l15;
        bf[i] = *(const u16x8*)(&Vs[(n * 8 + (k8 ^ (n & 7))) * 8]);
      }
#pragma unroll
      for (int mi = 0; mi < 4; ++mi)
#pragma unroll
        for (int ni = 0; ni < 4; ++ni)
          av[mi][ni] = mfma16(af[mi], bf[ni], av[mi][ni]);
    }
  }

  epi_store(ak, bk, 1.f, kh, bm, bn, 11, 0, sh, tid, wave, l15, quad);
  epi_store(av, bv, 1.f, vt, bm, bn, 11, 2, sh, tid, wave, l15, quad);
}

// Single-GEMM body (Q projection), mode 0 epilogue.
DEVI void q_body(const unsigned short* __restrict__ A,
                 const unsigned short* __restrict__ W,
                 const float* __restrict__ bias,
                 unsigned short* __restrict__ Cout,
                 int bm, int bn, unsigned short* sh) {
  constexpr int K = 1024;
  unsigned short* As = sh;
  unsigned short* Bs = sh + 128 * 64;

  const int tid = threadIdx.x;
  const int wave = tid >> 6, lane = tid & 63;
  const int l15 = lane & 15, quad = lane >> 4;
  const int wm = wave & 1, wn = wave >> 1;

  f32x4 acc[4][4] = {};

  for (int k0 = 0; k0 < K; k0 += 64) {
    __syncthreads();
#pragma unroll
    for (int c = 0; c < 4; ++c) {
      int s = c * 256 + tid;
      int m = s >> 3;
      int k8 = (s & 7) ^ (m & 7);
      llds16(A + (size_t)(bm + m) * K + k0 + k8 * 8, &As[s * 8]);
      llds16(W + (size_t)(bn + m) * K + k0 + k8 * 8, &Bs[s * 8]);
    }
    __syncthreads();
#pragma unroll
    for (int ks = 0; ks < 2; ++ks) {
      const int k8 = ks * 4 + quad;
      u16x8 af[4], bf[4];
#pragma unroll
      for (int i = 0; i < 4; ++i) {
        int m = wm * 64 + i * 16 + l15;
        af[i] = *(const u16x8*)(&As[(m * 8 + (k8 ^ (m & 7))) * 8]);
        int n = wn * 64 + i * 16 + l15;
        bf[i] = *(const u16x8*)(&Bs[(n * 8 + (k8 ^ (n & 7))) * 8]);
      }
#pragma unroll
      for (int mi = 0; mi < 4; ++mi)
#pragma unroll
        for (int ni = 0; ni < 4; ++ni)
          acc[mi][ni] = mfma16(af[mi], bf[ni], acc[mi][ni]);
    }
  }

  epi_store(acc, bias, QSC, Cout, bm, bn, 9, 0, sh, tid, wave, l15, quad);
}

// Fused Q/K/V projection. Grid (64, 10).
// y in [0,8): fused K+V tiles; y in {8,9}: Q tiles.
__global__ __launch_bounds__(256, 2)
void gemm_qkv(const unsigned short* __restrict__ xb,
              const unsigned short* __restrict__ cb,
              const unsigned short* __restrict__ wq,
              const unsigned short* __restrict__ wk,
              const unsigned short* __restrict__ wv,
              const float* __restrict__ bq, const float* __restrict__ bk,
              const float* __restrict__ bv,
              unsigned short* __restrict__ qh, unsigned short* __restrict__ kh,
              unsigned short* __restrict__ vt) {
  __shared__ __align__(16) unsigned short sh[128 * 64 * 3];  // 48 KB
  const int x = blockIdx.x, y = blockIdx.y;
  if (y < 8) {
    kv_body(cb, wk, wv, bk, bv, kh, vt, x * 128, y * 128, sh);
  } else {
    q_body(xb, wq, bq, qh, (x & 15) * 128, (y - 8) * 512 + (x >> 4) * 128, sh);
  }
}

// ---------------------------------------------------------------------------
// Output projection: out[2048,1024] fp32 = ah @ Wo^T + bo. 64x128 tile,
// grid (32, 8) = 256 blocks (one per CU), 4 waves each 64 rows x 32 cols.
__global__ __launch_bounds__(256)
void gemm_o(const unsigned short* __restrict__ A,
            const unsigned short* __restrict__ W,
            const float* __restrict__ bo, float* __restrict__ out) {
  constexpr int K = 1024;
  __shared__ __align__(16) unsigned short As[64 * 64];   // 8 KB
  __shared__ __align__(16) unsigned short Bs[128 * 64];  // 16 KB

  const int tid = threadIdx.x;
  const int wave = tid >> 6, lane = tid & 63;
  const int l15 = lane & 15, quad = lane >> 4;
  const int bm = blockIdx.x * 64, bn = blockIdx.y * 128;

  f32x4 acc[4][2] = {};

  for (int k0 = 0; k0 < K; k0 += 64) {
    __syncthreads();
#pragma unroll
    for (int c = 0; c < 2; ++c) {
      int s = c * 256 + tid;
      int m = s >> 3, k8 = (s & 7) ^ (m & 7);
      llds16(A + (size_t)(bm + m) * K + k0 + k8 * 8, &As[s * 8]);
    }
#pragma unroll
    for (int c = 0; c < 4; ++c) {
      int s = c * 256 + tid;
      int m = s >> 3, k8 = (s & 7) ^ (m & 7);
      llds16(W + (size_t)(bn + m) * K + k0 + k8 * 8, &Bs[s * 8]);
    }
    __syncthreads();
#pragma unroll
    for (int ks = 0; ks < 2; ++ks) {
      const int k8 = ks * 4 + quad;
      u16x8 af[4], bf[2];
#pragma unroll
      for (int i = 0; i < 4; ++i) {
        int m = i * 16 + l15;
        af[i] = *(const u16x8*)(&As[(m * 8 + (k8 ^ (m & 7))) * 8]);
      }
#pragma unroll
      for (int i = 0; i < 2; ++i) {
        int n = wave * 32 + i * 16 + l15;
        bf[i] = *(const u16x8*)(&Bs[(n * 8 + (k8 ^ (n & 7))) * 8]);
      }
#pragma unroll
      for (int mi = 0; mi < 4; ++mi)
#pragma unroll
        for (int ni = 0; ni < 2; ++ni)
          acc[mi][ni] = mfma16(af[mi], bf[ni], acc[mi][ni]);
    }
  }

#pragma unroll
  for (int mi = 0; mi < 4; ++mi)
#pragma unroll
    for (int ni = 0; ni < 2; ++ni)
#pragma unroll
      for (int r = 0; r < 4; ++r) {
        int row = bm + mi * 16 + quad * 4 + r;
        int col = bn + wave * 32 + ni * 16 + l15;
        out[(size_t)row * 1024 + col] = acc[mi][ni][r] + bo[col];
      }
}

// ---------------------------------------------------------------------------
// Split-K flash attention, fixed-max softmax. Grid (64 bh, 8 qblk), block 256.
// Wave w covers keys {w*64 + 256t}, t=0..7; no barriers in the main loop.
// SINGLE K-fragment buffer: kf(t+1) loads issue right after kf's last use
// (qg==3's S-MFMA), covered by softmax+PV (~450 cy). vf(t) loads at tile
// start, covered by S+softmax of qg0 (~400 cy). Keeps peak VGPR ~230 < 256
// (R5's double-buffer spilled to scratch: 4x write amplification).
// PS: p_lds row stride in u16. MUST be == 0 mod 8 (16 B) -- P fragments are
// read as u16x8 (ds_read_b128); any other stride misaligns odd q-rows.
#define PS 72
__global__ __launch_bounds__(256, 2)
void attn_kernel(const unsigned short* __restrict__ Q,   // [64][512][64]
                 const unsigned short* __restrict__ K,   // [64][2048][64]
                 const unsigned short* __restrict__ Vt,  // [64][64][2048]
                 const int* __restrict__ mask,           // [4][2048]
                 unsigned short* __restrict__ O) {       // [4][512][1024]
  __shared__ float bias_lds[2048];
  __shared__ __align__(16) unsigned short p_lds[4][2][16 * PS];
  __shared__ float l_lds[4][64];
  __shared__ __align__(16) float o_comb[64][68];

  const int tid = threadIdx.x;
  const int wave = tid >> 6, lane = tid & 63;
  const int l15 = lane & 15, quad = lane >> 4;
  const int bh = blockIdx.x, b = bh >> 4, h = bh & 15;
  const int q0 = blockIdx.y * 64;

  {  // mask -> additive bias in log2 units, with fixed max-shift -8 folded in
    const int* mb = mask + b * 2048;
    for (int i = tid; i < 2048; i += 256)
      bias_lds[i] = mb[i] ? -8.f : -1e30f;
  }
  __syncthreads();

  const unsigned short* Qb = Q + ((size_t)bh * 512 + q0) * 64;
  const unsigned short* Kb = K + (size_t)bh * (2048 * 64);
  const unsigned short* Vb = Vt + (size_t)bh * (64 * 2048);

  // Q fragments: lane l15 = q row, elements = d. Held all kernel.
  u16x8 aq[4][2];
#pragma unroll
  for (int qg = 0; qg < 4; ++qg)
#pragma unroll
    for (int ks = 0; ks < 2; ++ks)
      aq[qg][ks] = *(const u16x8*)(Qb + (qg * 16 + l15) * 64 + ks * 32 + quad * 8);

  f32x4 o_acc[4][4] = {};
  float l_s[4] = {0.f, 0.f, 0.f, 0.f};

  u16x8 kf[2][4];

  auto load_k = [&](int kb) {
#pragma unroll
    for (int ns = 0; ns < 4; ++ns)
#pragma unroll
      for (int ks = 0; ks < 2; ++ks)
        kf[ks][ns] = *(const u16x8*)(Kb + (size_t)(kb + ns * 16 + l15) * 64 + ks * 32 + quad * 8);
  };

  load_k(wave * 64);

#pragma unroll 1
  for (int t = 0; t < 8; ++t) {
    const int kb = wave * 64 + t * 256;
    const int kb_next = kb + (t < 7 ? 256 : 0);

    // V^T frags (B-op: lane=d, elems=key): consumed in PV, first use is
    // ~400 cy after issue (S + softmax of qg0).
    u16x8 vf[2][4];
#pragma unroll
    for (int nd = 0; nd < 4; ++nd)
#pragma unroll
      for (int ks = 0; ks < 2; ++ks)
        vf[ks][nd] = *(const u16x8*)(Vb + (size_t)(nd * 16 + l15) * 2048 + kb + ks * 32 + quad * 8);
    f32x4 bfr[4];
#pragma unroll
    for (int ns = 0; ns < 4; ++ns)
      bfr[ns] = *(const f32x4*)&bias_lds[kb + ns * 16 + quad * 4];

#pragma unroll
    for (int qg = 0; qg < 4; ++qg) {
      // S^T tile: D[key = ns*16+quad*4+r][q = l15], C-init = bias (-8 shift)
      f32x4 sfr[4];
#pragma unroll
      for (int ns = 0; ns < 4; ++ns) {
        f32x4 sa = bfr[ns];
#pragma unroll
        for (int ks = 0; ks < 2; ++ks)
          sa = mfma16(kf[ks][ns], aq[qg][ks], sa);
        sfr[ns] = sa;
      }

      // kf dead after qg==3's S: reload for next tile now (covered by the
      // remaining softmax + PV of this qg).
      if (qg == 3) load_k(kb_next);

      float rsum = 0.f;
#pragma unroll
      for (int ns = 0; ns < 4; ++ns) {
        unsigned int pr[4];
#pragma unroll
        for (int r = 0; r < 4; ++r) {
          float p = exp2_fast(sfr[ns][r]);
          unsigned int u = __builtin_bit_cast(unsigned int, p) & 0xffff0000u;
          rsum += __builtin_bit_cast(float, u);  // sum TRUNCATED p: consistent with PV
          pr[r] = u;
        }
        uint2 pw;
        pw.x = __builtin_amdgcn_perm(pr[1], pr[0], 0x07060302u);
        pw.y = __builtin_amdgcn_perm(pr[3], pr[2], 0x07060302u);
        *(uint2*)&p_lds[wave][qg & 1][l15 * PS + ns * 16 + quad * 4] = pw;
      }
      rsum += __shfl_xor(rsum, 16, 64);
      rsum += __shfl_xor(rsum, 32, 64);
      l_s[qg] += rsum;

      // PV: A = P (lane=q, elems=key) from p_lds; B = V^T frags
#pragma unroll
      for (int ks = 0; ks < 2; ++ks) {
        u16x8 pf = *(const u16x8*)&p_lds[wave][qg & 1][l15 * PS + ks * 32 + quad * 8];
#pragma unroll
        for (int nd = 0; nd < 4; ++nd)
          o_acc[qg][nd] = mfma16(pf, vf[ks][nd], o_acc[qg][nd]);
      }
    }
  }

  // ---- combine the 4 waves' partial (l, o): plain sums (fixed max) ----
  if (quad == 0) {
#pragma unroll
    for (int qg = 0; qg < 4; ++qg)
      l_lds[wave][qg * 16 + l15] = l_s[qg];
  }
  __syncthreads();

  for (int w = 0; w < 4; ++w) {
    if (wave == w) {
#pragma unroll
      for (int qg = 0; qg < 4; ++qg)
#pragma unroll
        for (int r = 0; r < 4; ++r) {
          const int q = qg * 16 + quad * 4 + r;
#pragma unroll
          for (int nd = 0; nd < 4; ++nd) {
            const int d = nd * 16 + l15;
            float v = o_acc[qg][nd][r];
            if (w == 0) o_comb[q][d] = v;
            else        o_comb[q][d] += v;
          }
        }
    }
    __syncthreads();
  }

  // ---- final normalize + store (two u16x8 per thread) ----
  {
    const int q = tid >> 2, dc = (tid & 3) * 16;
    const float inv = 1.f / (l_lds[0][q] + l_lds[1][q] + l_lds[2][q] + l_lds[3][q]);
    unsigned short* Ob = O + ((size_t)(b * 512 + q0 + q)) * 1024 + h * 64 + dc;
    u16x8 o1, o2;
#pragma unroll
    for (int j = 0; j < 8; ++j) o1[j] = f2bf(o_comb[q][dc + j] * inv);
#pragma unroll
    for (int j = 0; j < 8; ++j) o2[j] = f2bf(o_comb[q][dc + 8 + j] * inv);
    *(u16x8*)(Ob) = o1;
    *(u16x8*)(Ob + 8) = o2;
  }
}

// ---------------------------------------------------------------------------
extern "C" void kernel_launch(void* const* d_in, const int* in_sizes, int n_in,
                              void* d_out, int out_size, void* d_ws, size_t ws_size,
                              hipStream_t stream) {
  const float* x   = (const float*)d_in[0];
  const float* ctx = (const float*)d_in[1];
  const int* mask  = (const int*)d_in[2];
  const float* Wq  = (const float*)d_in[3];
  const float* bq  = (const float*)d_in[4];
  const float* Wk  = (const float*)d_in[5];
  const float* bk  = (const float*)d_in[6];
  const float* Wv  = (const float*)d_in[7];
  const float* bv  = (const float*)d_in[8];
  const float* Wo  = (const float*)d_in[9];
  const float* bo  = (const float*)d_in[10];

  char* ws = (char*)d_ws;
  // [MB] xb 0-4, cb 4-20, w 20-28, qh 28-32, kh 32-48, vt 48-64, ah 64-68.
  unsigned short* xb  = (unsigned short*)(ws + ((size_t)0  << 20));
  unsigned short* cb  = (unsigned short*)(ws + ((size_t)4  << 20));
  unsigned short* wqb = (unsigned short*)(ws + ((size_t)20 << 20));
  unsigned short* wkb = (unsigned short*)(ws + ((size_t)22 << 20));
  unsigned short* wvb = (unsigned short*)(ws + ((size_t)24 << 20));
  unsigned short* wob = (unsigned short*)(ws + ((size_t)26 << 20));
  unsigned short* qh  = (unsigned short*)(ws + ((size_t)28 << 20));
  unsigned short* kh  = (unsigned short*)(ws + ((size_t)32 << 20));
  unsigned short* vt  = (unsigned short*)(ws + ((size_t)48 << 20));
  unsigned short* ah  = (unsigned short*)(ws + ((size_t)64 << 20));

  cast_fused<<<14336, 256, 0, stream>>>(x, ctx, Wq, Wk, Wv, Wo,
                                        xb, cb, wqb, wkb, wvb, wob);
  gemm_qkv<<<dim3(64, 10), 256, 0, stream>>>(xb, cb, wqb, wkb, wvb,
                                             bq, bk, bv, qh, kh, vt);
  attn_kernel<<<dim3(64, 8), 256, 0, stream>>>(qh, kh, vt, mask, ah);
  gemm_o<<<dim3(32, 8), 256, 0, stream>>>(ah, wob, bo, (float*)d_out);
}